// Round 2
// baseline (365.763 us; speedup 1.0000x reference)
//
#include <hip/hip_runtime.h>
#include <math.h>

#define KK 17
#define TT 512
#define DD 1024
#define NBATCH 64
#define NEGC -10000.0f
#define NINF -1e30f

__device__ __forceinline__ float wsum64(float v) {
#pragma unroll
  for (int s = 32; s >= 1; s >>= 1) v += __shfl_xor(v, s);
  return v;
}
__device__ __forceinline__ float wmax64(float v) {
#pragma unroll
  for (int s = 32; s >= 1; s >>= 1) v = fmaxf(v, __shfl_xor(v, s));
  return v;
}
__device__ __forceinline__ int wsum64i(int v) {
#pragma unroll
  for (int s = 32; s >= 1; s >>= 1) v += __shfl_xor(v, s);
  return v;
}

// ---------------- Kernel 1: logits = X @ W + b ----------------
// 512 threads/block; each wave computes TWO rows (halves LDS reads per row,
// keeping us HBM-bound instead of LDS-issue-bound).
// W staged in LDS in two K-halves (stride 17 -> 2-way bank aliasing = free).
__global__ __launch_bounds__(512) void k_logits(const float* __restrict__ X,
                                                const float* __restrict__ W,
                                                const float* __restrict__ b,
                                                float* __restrict__ logits) {
  __shared__ float Ws[512 * KK];  // 34816 B -> 4 blocks/CU, full occupancy
  const int tid = threadIdx.x;
  const int lane = tid & 63;
  const int wv = tid >> 6;
  const long r0 = (long)blockIdx.x * 16 + wv * 2;
  const float* x0 = X + r0 * DD;
  float a0[KK], a1[KK];
#pragma unroll
  for (int j = 0; j < KK; ++j) { a0[j] = 0.f; a1[j] = 0.f; }

  for (int half = 0; half < 2; ++half) {
    __syncthreads();  // protect previous half's use before restage
#pragma unroll
    for (int i = 0; i < KK; ++i) {
      int idx = tid + i * 512;
      Ws[idx] = W[half * 512 * KK + idx];
    }
    __syncthreads();
#pragma unroll
    for (int it = 0; it < 8; ++it) {
      int k = it * 64 + lane;                    // local k within half
      float xa = x0[half * 512 + k];             // coalesced dword loads
      float xb = x0[DD + half * 512 + k];
#pragma unroll
      for (int j = 0; j < KK; ++j) {
        float w = Ws[k * KK + j];                // one LDS read feeds 2 FMAs
        a0[j] = fmaf(xa, w, a0[j]);
        a1[j] = fmaf(xb, w, a1[j]);
      }
    }
  }
#pragma unroll
  for (int j = 0; j < KK; ++j) { a0[j] = wsum64(a0[j]); a1[j] = wsum64(a1[j]); }
  if (lane < KK) {
    float v0 = 0.f, v1 = 0.f;
#pragma unroll
    for (int j = 0; j < KK; ++j)
      if (lane == j) { v0 = a0[j]; v1 = a1[j]; }  // static-index select
    float bb = b[lane];
    logits[r0 * KK + lane] = v0 + bb;
    logits[(r0 + 1) * KK + lane] = v1 + bb;
  }
}

// ---------------- Kernel 2: scans ----------------
// grid 128 x 128 threads. batch = blockIdx&63, role = blockIdx>>6.
// role 0: wave0 = scaled forward (logZ), wave1 = gold score; atomicAdd loss.
// role 1: wave0 = constrained viterbi (+bp in LDS); log-doubling backtrace; pred.
__global__ __launch_bounds__(128) void k_scan(
    const float* __restrict__ logits, const void* __restrict__ maskp,
    const int* __restrict__ gold, const float* __restrict__ trans,
    const float* __restrict__ st, const float* __restrict__ et,
    const float* __restrict__ ta, const float* __restrict__ sa,
    const float* __restrict__ ea, float* __restrict__ lossp,
    float* __restrict__ predp) {
  __shared__ __align__(16) float EM[513 * KK];  // emissions (raw or exp'd); +1 pad row
  __shared__ __align__(4) unsigned char Mk[512];
  __shared__ unsigned char BPt[511 * KK];
  __shared__ unsigned char G2t[256 * KK];
  __shared__ unsigned char G4t[128 * KK];
  __shared__ unsigned char G8t[64 * KK];
  __shared__ unsigned char PR[512];
  __shared__ float red[2];
  __shared__ int slen[2];
  __shared__ int shlt;

  const int tid = threadIdx.x;
  const int lane = tid & 63;
  const int wv = tid >> 6;
  const int batch = blockIdx.x & 63;
  const int role = blockIdx.x >> 6;
  const float* Lg = logits + (size_t)batch * TT * KK;

  // ---- mask dtype detection: lengths>=128 so mask[0][1]==1. As byte-bool,
  // byte 1 of the buffer is 1; as int32 (value 0/1), byte 1 is 0. Never OOB.
  const unsigned char* mb = (const unsigned char*)maskp;
  const bool m_is_i32 = (mb[1] == 0);

  // ---- stage emissions (exp'd for role 0) and mask ----
  {
    const float4* Lg4 = reinterpret_cast<const float4*>(Lg);
    float4* EM4 = reinterpret_cast<float4*>(EM);
    for (int i = tid; i < (TT * KK) / 4; i += 128) {
      float4 v = Lg4[i];
      if (role == 0) {
        v.x = expf(v.x); v.y = expf(v.y); v.z = expf(v.z); v.w = expf(v.w);
      }
      EM4[i] = v;
    }
    if (m_is_i32) {
      const int* mi = (const int*)maskp + batch * TT;
      for (int t2 = tid; t2 < TT; t2 += 128) Mk[t2] = (unsigned char)(mi[t2] != 0);
    } else {
      const unsigned char* mB = mb + batch * TT;
      for (int t2 = tid; t2 < TT; t2 += 128) Mk[t2] = (unsigned char)(mB[t2] != 0);
    }
  }
  __syncthreads();
  // ---- length (mask is a contiguous prefix of ones) ----
  {
    unsigned int m4 = *reinterpret_cast<const unsigned int*>(&Mk[tid * 4]);
    int c = (int)((m4 * 0x01010101u) >> 24);  // sum of 4 bytes (each 0/1)
    c = wsum64i(c);
    if (lane == 0) slen[wv] = c;
  }
  __syncthreads();
  const int len = slen[0] + slen[1];

  if (role == 0) {
    if (wv == 0) {
      // ---------- scaled forward: q_t = (q_{t-1} . P) * exp(emit_t) ----------
      const int jc = lane < KK ? lane : (KK - 1);
      const bool act = lane < KK;
      float Pcol[KK];
#pragma unroll
      for (int i = 0; i < KK; ++i) Pcol[i] = expf(trans[i * KK + jc]);
      float a0 = st[jc] + Lg[jc];  // raw logits t=0 (EM is exp'd here)
      float m0 = wmax64(act ? a0 : NINF);
      float qown = expf(a0 - m0);
      float C = m0;
      float q[KK];
#pragma unroll
      for (int i = 0; i < KK; ++i) q[i] = __shfl(qown, i);
      float ee = EM[KK + jc];  // exp(emit[1])
      for (int t = 1; t < len; ++t) {
        float ee_n = EM[(t + 1) * KK + jc];  // pad row makes t=len-1 safe
        float da = fmaf(q[0], Pcol[0], fmaf(q[4], Pcol[4], fmaf(q[8], Pcol[8], fmaf(q[12], Pcol[12], q[16] * Pcol[16]))));
        float db = fmaf(q[1], Pcol[1], fmaf(q[5], Pcol[5], fmaf(q[9], Pcol[9], q[13] * Pcol[13])));
        float dc = fmaf(q[2], Pcol[2], fmaf(q[6], Pcol[6], fmaf(q[10], Pcol[10], q[14] * Pcol[14])));
        float dd = fmaf(q[3], Pcol[3], fmaf(q[7], Pcol[7], fmaf(q[11], Pcol[11], q[15] * Pcol[15])));
        float qn = ((da + db) + (dc + dd)) * ee;
        ee = ee_n;
#pragma unroll
        for (int i = 0; i < KK; ++i) q[i] = __shfl(qn, i);
        qown = qn;
        if ((t & 7) == 0) {  // renormalize; growth bounded, safe in fp32
          float s0 = ((q[0] + q[1]) + (q[2] + q[3])) + ((q[4] + q[5]) + (q[6] + q[7]));
          float s1 = ((q[8] + q[9]) + (q[10] + q[11])) + ((q[12] + q[13]) + (q[14] + q[15]));
          float s = (s0 + s1) + q[16];
          float inv = 1.0f / s;
          C += logf(s);
#pragma unroll
          for (int i = 0; i < KK; ++i) q[i] *= inv;
          qown *= inv;
        }
      }
      float term = act ? qown * expf(et[jc]) : 0.f;
      float S = wsum64(term);
      if (lane == 0) red[0] = C + logf(S);  // logZ
    } else {
      // ---------- gold path score ----------
      const int* gb = gold + batch * TT;
      float esum = 0.f, tsum = 0.f;
#pragma unroll
      for (int u = 0; u < 8; ++u) {
        int t = lane + 64 * u;
        int gt = gb[t];
        float mt = (float)Mk[t];
        esum += mt * Lg[t * KK + gt];  // includes ref's last_emit term
        int tn = (t + 1 < TT) ? t + 1 : TT - 1;
        int gn = gb[tn];
        float mtr = (t + 1 < TT && Mk[t + 1]) ? 1.f : 0.f;
        tsum += mtr * trans[gt * KK + gn];
      }
      float ssum = wsum64(esum + tsum);
      if (lane == 0) red[1] = ssum + st[gb[0]] + et[gb[len - 1]];  // score
    }
    __syncthreads();
    if (tid == 0) atomicAdd(lossp, red[0] - red[1]);  // loss = sum(logZ - score)
  } else {
    // ---------- constrained viterbi (wave 0), i split over two 32-lane halves ----------
    if (wv == 0) {
      const int jj = lane & 31;
      const int h = lane >> 5;
      const int jc = jj < KK ? jj : (KK - 1);
      const int i0 = h ? 9 : 0;
      const int ni = h ? 8 : 9;
      float ctv[9];
#pragma unroll
      for (int r = 0; r < 9; ++r) {
        int i = i0 + r;
        int ic = i < KK ? i : (KK - 1);
        float cv = (ta[ic * KK + jc] > 0.5f) ? trans[ic * KK + jc] : NEGC;
        ctv[r] = (r < ni) ? cv : NINF;
      }
      float v = ((sa[jc] > 0.5f) ? st[jc] : NEGC) + EM[jc];
      float ec = EM[KK + jc];
      for (int t = 1; t < len; ++t) {
        float en = EM[(t + 1) * KK + jc];
        float c0 = __shfl(v, i0 + 0) + ctv[0];
        float c1 = __shfl(v, i0 + 1) + ctv[1];
        float c2 = __shfl(v, i0 + 2) + ctv[2];
        float c3 = __shfl(v, i0 + 3) + ctv[3];
        float c4 = __shfl(v, i0 + 4) + ctv[4];
        float c5 = __shfl(v, i0 + 5) + ctv[5];
        float c6 = __shfl(v, i0 + 6) + ctv[6];
        float c7 = __shfl(v, i0 + 7) + ctv[7];
        float c8 = __shfl(v, i0 + 8) + ctv[8];
        // strict '>' keeps lower index on ties (matches np.argmax first-max)
        float v01 = c1 > c0 ? c1 : c0; int i01 = c1 > c0 ? i0 + 1 : i0;
        float v23 = c3 > c2 ? c3 : c2; int i23 = c3 > c2 ? i0 + 3 : i0 + 2;
        float v45 = c5 > c4 ? c5 : c4; int i45 = c5 > c4 ? i0 + 5 : i0 + 4;
        float v67 = c7 > c6 ? c7 : c6; int i67 = c7 > c6 ? i0 + 7 : i0 + 6;
        float v03 = v23 > v01 ? v23 : v01; int i03 = v23 > v01 ? i23 : i01;
        float v47 = v67 > v45 ? v67 : v45; int i47 = v67 > v45 ? i67 : i45;
        float v07 = v47 > v03 ? v47 : v03; int i07 = v47 > v03 ? i47 : i03;
        float bv = c8 > v07 ? c8 : v07;   int bi = c8 > v07 ? i0 + 8 : i07;
        float ov = __shfl_xor(bv, 32);
        int oi = __shfl_xor(bi, 32);
        bool take = (ov > bv) || (ov == bv && oi < bi);
        bv = take ? ov : bv;
        bi = take ? oi : bi;
        BPt[(t - 1) * KK + jc] = (unsigned char)bi;
        v = bv + ec;
        ec = en;
      }
      float fv = (jj < KK) ? (v + ((ea[jc] > 0.5f) ? et[jc] : NEGC)) : NINF;
      int fi = jc;
#pragma unroll
      for (int s = 32; s >= 1; s >>= 1) {
        float ov = __shfl_xor(fv, s); int oi = __shfl_xor(fi, s);
        bool take = (ov > fv) || (ov == fv && oi < fi);
        fv = take ? ov : fv; fi = take ? oi : fi;
      }
      if (tid == 0) shlt = fi;
    }
    __syncthreads();
    const int lt = shlt;
    // ---- compose backpointer maps: g_s(x) = mask[s+1] ? bp[s][x] : x ----
    for (int m = tid; m < 256; m += 128) {
      int s1 = 2 * m + 1, s0 = 2 * m;
      bool u1 = (s1 < 511) && Mk[s1 + 1];
      bool u0 = Mk[s0 + 1] != 0;
#pragma unroll
      for (int x = 0; x < KK; ++x) {
        int y = u1 ? (int)BPt[s1 * KK + x] : x;
        int z = u0 ? (int)BPt[s0 * KK + y] : y;
        G2t[m * KK + x] = (unsigned char)z;
      }
    }
    __syncthreads();
    {
      int p = tid;  // 0..127
#pragma unroll
      for (int x = 0; x < KK; ++x) {
        int y = G2t[(2 * p + 1) * KK + x];
        G4t[p * KK + x] = G2t[2 * p * KK + y];
      }
    }
    __syncthreads();
    if (tid < 64) {
      int p = tid;
#pragma unroll
      for (int x = 0; x < KK; ++x) {
        int y = G4t[(2 * p + 1) * KK + x];
        G8t[p * KK + x] = G4t[2 * p * KK + y];
      }
    }
    __syncthreads();
    if (tid == 0) {  // serial chain: only 64 dependent LDS lookups
      int x = lt;
      for (int p = 63; p >= 0; --p) {
        x = G8t[p * KK + x];
        PR[8 * p] = (unsigned char)x;
      }
    }
    __syncthreads();
    if (tid < 64) {
      int p = tid;
      int src = (p == 63) ? lt : (int)PR[8 * p + 8];
      PR[8 * p + 4] = G4t[(2 * p + 1) * KK + src];
    }
    __syncthreads();
    {
      int m = tid;
      int src = (m == 127) ? lt : (int)PR[4 * m + 4];
      PR[4 * m + 2] = G2t[(2 * m + 1) * KK + src];
    }
    __syncthreads();
    for (int m = tid; m < 256; m += 128) {
      int s = 2 * m + 1;
      int src = (m == 255) ? lt : (int)PR[2 * m + 2];
      int val = ((s < 511) && Mk[s + 1]) ? (int)BPt[s * KK + src] : src;
      PR[2 * m + 1] = (unsigned char)val;
    }
    __syncthreads();
    float* po = predp + batch * TT;
    for (int t2 = tid; t2 < TT; t2 += 128) po[t2] = Mk[t2] ? (float)PR[t2] : 0.f;
  }
}

extern "C" void kernel_launch(void* const* d_in, const int* in_sizes, int n_in,
                              void* d_out, int out_size, void* d_ws, size_t ws_size,
                              hipStream_t stream) {
  const float* mlm = (const float*)d_in[0];
  const void* mask = d_in[1];  // bool: byte or int32 — detected on device
  const int* gold = (const int*)d_in[2];
  const float* W = (const float*)d_in[3];
  const float* b = (const float*)d_in[4];
  const float* trans = (const float*)d_in[5];
  const float* st = (const float*)d_in[6];
  const float* et = (const float*)d_in[7];
  const float* ta = (const float*)d_in[8];
  const float* sa = (const float*)d_in[9];
  const float* ea = (const float*)d_in[10];

  float* out = (float*)d_out;
  float* logits = out;                             // [64*512*17]
  float* lossp = out + (size_t)NBATCH * TT * KK;   // [1]
  float* predp = lossp + 1;                        // [64*512]

  hipMemsetAsync(lossp, 0, sizeof(float), stream);
  k_logits<<<dim3(2048), dim3(512), 0, stream>>>(mlm, W, b, logits);
  k_scan<<<dim3(128), dim3(128), 0, stream>>>(logits, mask, gold, trans, st, et,
                                              ta, sa, ea, lossp, predp);
}